// Round 1
// baseline (136.390 us; speedup 1.0000x reference)
//
#include <hip/hip_runtime.h>
#include <hip/hip_bf16.h>

#define NROWS 8192
#define KDIM  256
#define NT    64                  // NROWS / 128
#define NBLK  (NT * (NT + 1) / 2) // 2080 upper-triangular 128x128 tiles
#define GRID  256                 // persistent blocks; 8-9 tiles each

typedef __attribute__((ext_vector_type(4))) float f32x4;

// async global->LDS, 16B per lane; LDS dest is wave-uniform base + lane*16
#define GLD(gp, lp)                                                            \
  __builtin_amdgcn_global_load_lds(                                            \
      (const __attribute__((address_space(1))) void*)(gp),                     \
      (__attribute__((address_space(3))) void*)(lp), 16, 0, 0)

// ---------------------------------------------------------------------------
// Kernel 1: fp32 -> fp8 e4m3 (OCP) convert + per-row sum of squares (fp32).
// ---------------------------------------------------------------------------
__global__ void prep_kernel(const float* __restrict__ samples,
                            unsigned char* __restrict__ sf8,
                            float* __restrict__ sq,
                            float* __restrict__ accg) {
  int row = blockIdx.x, t = threadIdx.x;  // t in [0,128)
  float2 v2 = ((const float2*)samples)[(size_t)row * 128 + t];
  int pk = __builtin_amdgcn_cvt_pk_fp8_f32(v2.x, v2.y, 0, false);
  ((unsigned short*)sf8)[(size_t)row * 128 + t] = (unsigned short)(pk & 0xffff);
  float p = v2.x * v2.x + v2.y * v2.y;
#pragma unroll
  for (int off = 32; off; off >>= 1) p += __shfl_down(p, off);
  __shared__ float ws2[2];
  if ((t & 63) == 0) ws2[t >> 6] = p;
  __syncthreads();
  if (t == 0) sq[row] = ws2[0] + ws2[1];
  if (row == 0 && t < 2) accg[t] = 0.0f;
}

// decode triangular block index b -> (bi, bj), bi <= bj  (verified absmax 0.0)
__device__ inline void decode_tile(int b, int& bi, int& bj) {
  float disc = (2.0f * NT + 1.0f) * (2.0f * NT + 1.0f) - 8.0f * (float)b;
  bi = (int)(((2.0f * NT + 1.0f) - sqrtf(disc)) * 0.5f);
  if (bi < 0) bi = 0;
  if (bi > NT - 1) bi = NT - 1;
  while (bi > 0 && (bi * NT - bi * (bi - 1) / 2) > b) --bi;
  while (((bi + 1) * NT - (bi + 1) * bi / 2) <= b) ++bi;
  bj = bi + (b - (bi * NT - bi * (bi - 1) / 2));
}

// ---------------------------------------------------------------------------
// Kernel 2: persistent blocks, tile-level double-buffered fp8 Gram tiles.
// 512 threads = 8 waves, each wave a 32x64 quadrant (2x4 grid of 16x16x32).
// Per tile: ONE barrier; next tile's 64KB prefetch (async GLD) flies behind
// the MFMA phase. Loss terms accumulate in registers across tiles; one
// reduction + 2 atomics per block at the very end.
// ---------------------------------------------------------------------------
__global__ __launch_bounds__(512, 1) void pair_kernel(
    const unsigned char* __restrict__ sf8, const float* __restrict__ sq,
    const int* __restrict__ labels, float* __restrict__ accg) {

  __shared__ __align__(16) unsigned char As[2][128 * 256];
  __shared__ __align__(16) unsigned char Bs[2][128 * 256];
  __shared__ float red[16];

  int t = threadIdx.x;
  int lane = t & 63;
  int w = t >> 6;            // 0..7
  int wm = w >> 1, wn = w & 1;  // wave quadrant: rows wm*32+, cols wn*64+
  int lr = lane >> 4, pc = lane & 15;  // staging: row-in-region, phys chunk
  int r = lane & 15;                    // fragment row within 16
  int kq = (lane >> 4) >> 1;
  int hf = ((lane >> 4) & 1) * 8;
  int q4 = (lane >> 4) * 4;
  int cl = lane & 15;

  float s1t = 0.f, s2t = 0.f;

  // stage tile (bi,bj) into buffer `buf`: 32 regions x 1KB per matrix,
  // XOR-16B swizzle applied on the GLOBAL side (LDS base stays wave-uniform)
  auto stage = [&](int bi_, int bj_, int buf) {
    int rA = bi_ * 128, rB = bj_ * 128;
#pragma unroll
    for (int p = 0; p < 4; ++p) {
      int region = p * 8 + w;
      int rr = region * 4 + lr;
      int c = pc ^ (rr & 15);
      GLD(sf8 + (size_t)(rA + rr) * KDIM + c * 16, &As[buf][region * 1024]);
      GLD(sf8 + (size_t)(rB + rr) * KDIM + c * 16, &Bs[buf][region * 1024]);
    }
  };

  int tile = blockIdx.x;
  int bi, bj;
  decode_tile(tile, bi, bj);
  stage(bi, bj, 0);
  int cur = 0;

  while (tile < NBLK) {
    int ntile = tile + GRID;
    int nbi = 0, nbj = 0;
    bool have_next = ntile < NBLK;
    if (have_next) decode_tile(ntile, nbi, nbj);

    __syncthreads();  // buf[cur] staging complete (vmcnt drain at barrier)

    // epilogue scalars for CUR tile -- issued BEFORE the prefetch GLDs so
    // their (in-order) vmcnt waits don't force prefetch completion
    int rowA0 = bi * 128, rowB0 = bj * 128;
    float sqa[8], sqb[4];
    int laa[8], lab[4];
#pragma unroll
    for (int i = 0; i < 2; i++)
#pragma unroll
      for (int q = 0; q < 4; q++) {
        int gr = rowA0 + wm * 32 + i * 16 + q4 + q;
        sqa[i * 4 + q] = sq[gr];
        laa[i * 4 + q] = labels[gr];
      }
#pragma unroll
    for (int j = 0; j < 4; j++) {
      int gc = rowB0 + wn * 64 + j * 16 + cl;
      sqb[j] = sq[gc];
      lab[j] = labels[gc];
    }

    if (have_next) stage(nbi, nbj, cur ^ 1);  // async prefetch, other buffer

    // ---- barrier-free MFMA phase on buf[cur] ----
    f32x4 acc[2][4];
#pragma unroll
    for (int i = 0; i < 2; i++)
#pragma unroll
      for (int j = 0; j < 4; j++) acc[i][j] = (f32x4){0.f, 0.f, 0.f, 0.f};

#pragma unroll
    for (int kc = 0; kc < 8; ++kc) {
      long af[2], bfr[4];
#pragma unroll
      for (int i = 0; i < 2; i++) {
        int m = wm * 32 + i * 16 + r;
        af[i] = *(const long*)(&As[cur][m * 256 + (((kc * 2 + kq) ^ r) * 16) + hf]);
      }
#pragma unroll
      for (int j = 0; j < 4; j++) {
        int n = wn * 64 + j * 16 + r;
        bfr[j] = *(const long*)(&Bs[cur][n * 256 + (((kc * 2 + kq) ^ r) * 16) + hf]);
      }
#pragma unroll
      for (int i = 0; i < 2; i++)
#pragma unroll
        for (int j = 0; j < 4; j++)
          acc[i][j] = __builtin_amdgcn_mfma_f32_16x16x32_fp8_fp8(
              af[i], bfr[j], acc[i][j], 0, 0, 0);
    }

    // ---- epilogue: gram -> S -> masked sums, accumulate in registers ----
    // C/D layout: col = lane&15 (n), row = (lane>>4)*4 + reg (m)
    float s1 = 0.f, s2 = 0.f;
#pragma unroll
    for (int j = 0; j < 4; j++) {
#pragma unroll
      for (int i = 0; i < 2; i++) {
#pragma unroll
        for (int q = 0; q < 4; q++) {
          float S = (sqa[i * 4 + q] + sqb[j] - 2.0f * acc[i][j][q]) *
                    (1.0f / 256.0f);
          if (laa[i * 4 + q] == lab[j]) s1 += S;
          else                          s2 += fmaxf(0.f, 1.f - S);
        }
      }
    }
    float wt = (bi == bj) ? 1.0f : 2.0f;  // off-diagonal tiles count twice
    s1t += wt * s1;
    s2t += wt * s2;

    tile = ntile; bi = nbi; bj = nbj; cur ^= 1;
  }

  // ---- once per block: reduce 8 waves, 2 atomics ----
#pragma unroll
  for (int off = 32; off; off >>= 1) {
    s1t += __shfl_down(s1t, off);
    s2t += __shfl_down(s2t, off);
  }
  if (lane == 0) { red[w] = s1t; red[8 + w] = s2t; }
  __syncthreads();
  if (t == 0) {
    float a = 0.f, b2 = 0.f;
#pragma unroll
    for (int k = 0; k < 8; k++) { a += red[k]; b2 += red[8 + k]; }
    atomicAdd(&accg[0], a);
    atomicAdd(&accg[1], b2);
  }
}

// ---------------------------------------------------------------------------
// Kernel 3: final scalar
// ---------------------------------------------------------------------------
__global__ void finalize_kernel(const float* __restrict__ accg,
                                float* __restrict__ out) {
  out[0] = 10.0f * (accg[0] + accg[1]) *
           (1.0f / ((float)NROWS * (float)NROWS));
}

extern "C" void kernel_launch(void* const* d_in, const int* in_sizes, int n_in,
                              void* d_out, int out_size, void* d_ws,
                              size_t ws_size, hipStream_t stream) {
  // inputs: 0=merged (unused), 1=input1 (unused), 2=samples, 3=labels
  const float* samples = (const float*)d_in[2];
  const int*   labels  = (const int*)d_in[3];

  char* ws = (char*)d_ws;
  unsigned char* sf8 = (unsigned char*)ws;                        // 2 MiB fp8
  float* sq   = (float*)(ws + (size_t)NROWS * KDIM);              // 32 KiB
  float* accg = (float*)(ws + (size_t)NROWS * KDIM + NROWS * 4);  // 8 B
  float* out  = (float*)d_out;

  prep_kernel<<<NROWS, 128, 0, stream>>>(samples, sf8, sq, accg);
  pair_kernel<<<GRID, 512, 0, stream>>>(sf8, sq, labels, accg);
  finalize_kernel<<<1, 1, 0, stream>>>(accg, out);
}

// Round 2
// 124.585 us; speedup vs baseline: 1.0947x; 1.0947x over previous
//
#include <hip/hip_runtime.h>

#define NROWS 8192
#define KDIM  256
#define NT    64                  // NROWS / 128
#define NBLK  (NT * (NT + 1) / 2) // 2080 upper-triangular 128x128 tiles
#define GRID  256                 // persistent blocks; 8-9 tiles each

typedef __attribute__((ext_vector_type(4)))  float f32x4;
typedef __attribute__((ext_vector_type(16))) float f32x16;
typedef __attribute__((ext_vector_type(4)))  int   i32x4;
typedef __attribute__((ext_vector_type(8)))  int   i32x8;

// async global->LDS, 16B per lane; LDS dest is wave-uniform base + lane*16
#define GLD(gp, lp)                                                            \
  __builtin_amdgcn_global_load_lds(                                            \
      (const __attribute__((address_space(1))) void*)(gp),                     \
      (__attribute__((address_space(3))) void*)(lp), 16, 0, 0)

// ---------------------------------------------------------------------------
// Kernel 1: fp32 -> fp8 e4m3 (OCP) convert + per-row meta {sumsq/256, label}.
// ---------------------------------------------------------------------------
__global__ void prep_kernel(const float* __restrict__ samples,
                            const int* __restrict__ labels,
                            unsigned char* __restrict__ sf8,
                            float2* __restrict__ meta,
                            float* __restrict__ accg) {
  int row = blockIdx.x, t = threadIdx.x;  // t in [0,128)
  float2 v2 = ((const float2*)samples)[(size_t)row * 128 + t];
  int pk = __builtin_amdgcn_cvt_pk_fp8_f32(v2.x, v2.y, 0, false);
  ((unsigned short*)sf8)[(size_t)row * 128 + t] = (unsigned short)(pk & 0xffff);
  float p = v2.x * v2.x + v2.y * v2.y;
#pragma unroll
  for (int off = 32; off; off >>= 1) p += __shfl_down(p, off);
  __shared__ float ws2[2];
  if ((t & 63) == 0) ws2[t >> 6] = p;
  __syncthreads();
  if (t == 0) {
    float tot = ws2[0] + ws2[1];
    meta[row] = make_float2(tot * (1.0f / 256.0f), (float)labels[row]);
  }
  if (row == 0 && t < 2) accg[t] = 0.0f;
}

// decode triangular block index b -> (bi, bj), bi <= bj  (verified absmax 0.0)
__device__ inline void decode_tile(int b, int& bi, int& bj) {
  float disc = (2.0f * NT + 1.0f) * (2.0f * NT + 1.0f) - 8.0f * (float)b;
  bi = (int)(((2.0f * NT + 1.0f) - sqrtf(disc)) * 0.5f);
  if (bi < 0) bi = 0;
  if (bi > NT - 1) bi = NT - 1;
  while (bi > 0 && (bi * NT - bi * (bi - 1) / 2) > b) --bi;
  while (((bi + 1) * NT - (bi + 1) * bi / 2) <= b) ++bi;
  bj = bi + (b - (bi * NT - bi * (bi - 1) / 2));
}

// ---------------------------------------------------------------------------
// Kernel 2: persistent blocks, tile-level double-buffered fp8 Gram tiles.
// 512 threads = 8 waves, each wave a 32x64 quadrant (1x2 grid of 32x32x64
// MX-scaled MFMA at 2.3x the non-scaled fp8 rate; scale = e8m0 127 = 1.0,
// numerically identical to plain fp8 MFMA).
// Per tile: ONE barrier; next tile's 64KB prefetch (async GLD) flies behind
// the MFMA phase. Loss accumulates in ONE register across tiles (s1+s2 are
// only ever used summed); one reduction + 1 atomic per block at the end.
// ---------------------------------------------------------------------------
__global__ __launch_bounds__(512, 1) void pair_kernel(
    const unsigned char* __restrict__ sf8, const float2* __restrict__ meta,
    float* __restrict__ accg) {

  __shared__ __align__(16) unsigned char As[2][128 * 256];
  __shared__ __align__(16) unsigned char Bs[2][128 * 256];
  __shared__ float red[8];

  int t = threadIdx.x;
  int lane = t & 63;
  int w = t >> 6;               // 0..7
  int wm = w >> 1, wn = w & 1;  // wave quadrant: rows wm*32+, cols wn*64+
  int lr = lane >> 4, pc = lane & 15;  // staging: row-in-region, phys chunk
  int l31 = lane & 31;                 // fragment row/col within 32
  int hk  = lane >> 5;                 // k-half selector (0/1)

  float stt = 0.f;

  // stage tile (bi,bj) into buffer `buf`: 32 regions x 1KB per matrix,
  // XOR-16B swizzle applied on the GLOBAL side (LDS base stays wave-uniform)
  auto stage = [&](int bi_, int bj_, int buf) {
    int rA = bi_ * 128, rB = bj_ * 128;
#pragma unroll
    for (int p = 0; p < 4; ++p) {
      int region = p * 8 + w;
      int rr = region * 4 + lr;
      int c = pc ^ (rr & 15);
      GLD(sf8 + (size_t)(rA + rr) * KDIM + c * 16, &As[buf][region * 1024]);
      GLD(sf8 + (size_t)(rB + rr) * KDIM + c * 16, &Bs[buf][region * 1024]);
    }
  };

  int tile = blockIdx.x;
  int bi, bj;
  decode_tile(tile, bi, bj);
  stage(bi, bj, 0);
  int cur = 0;

  while (tile < NBLK) {
    int ntile = tile + GRID;
    int nbi = 0, nbj = 0;
    bool have_next = ntile < NBLK;
    if (have_next) decode_tile(ntile, nbi, nbj);

    __syncthreads();  // buf[cur] staging complete (vmcnt drain at barrier)

    // epilogue scalars for CUR tile -- issued BEFORE the prefetch GLDs so
    // their (in-order) vmcnt waits don't force prefetch completion.
    // C/D layout (32x32): col = lane&31, row = (reg&3)+8*(reg>>2)+4*(lane>>5)
    int rowA0 = bi * 128, rowB0 = bj * 128;
    float sqa_s[16], laaf[16];
#pragma unroll
    for (int g = 0; g < 4; ++g) {
      int gr = rowA0 + wm * 32 + g * 8 + 4 * hk;  // rows gr..gr+3
      f32x4 m0 = *(const f32x4*)(meta + gr);
      f32x4 m1 = *(const f32x4*)(meta + gr + 2);
      sqa_s[g * 4 + 0] = m0.x; laaf[g * 4 + 0] = m0.y;
      sqa_s[g * 4 + 1] = m0.z; laaf[g * 4 + 1] = m0.w;
      sqa_s[g * 4 + 2] = m1.x; laaf[g * 4 + 2] = m1.y;
      sqa_s[g * 4 + 3] = m1.z; laaf[g * 4 + 3] = m1.w;
    }
    float sqb_s[2], labf[2];
#pragma unroll
    for (int j = 0; j < 2; ++j) {
      float2 mb = meta[rowB0 + wn * 64 + j * 32 + l31];
      sqb_s[j] = mb.x; labf[j] = mb.y;
    }

    if (have_next) stage(nbi, nbj, cur ^ 1);  // async prefetch, other buffer

    // ---- barrier-free MFMA phase on buf[cur]: 8x mfma 32x32x64 fp8 (MX) ----
    f32x16 acc[2];
#pragma unroll
    for (int j = 0; j < 2; ++j)
#pragma unroll
      for (int e = 0; e < 16; ++e) acc[j][e] = 0.f;

#pragma unroll
    for (int kt = 0; kt < 4; ++kt) {
      int c0 = kt * 4 + hk * 2;  // logical 16B-chunk pair for this lane
      int m = wm * 32 + l31;
      const unsigned char* ab = &As[cur][m * 256];
      int sm = m & 15;
      i32x4 alo = *(const i32x4*)(ab + ((c0 ^ sm) << 4));
      i32x4 ahi = *(const i32x4*)(ab + (((c0 + 1) ^ sm) << 4));
      i32x8 av = {alo.x, alo.y, alo.z, alo.w, ahi.x, ahi.y, ahi.z, ahi.w};
#pragma unroll
      for (int j = 0; j < 2; ++j) {
        int n = wn * 64 + j * 32 + l31;
        const unsigned char* bb = &Bs[cur][n * 256];
        int sn = n & 15;
        i32x4 blo = *(const i32x4*)(bb + ((c0 ^ sn) << 4));
        i32x4 bhi = *(const i32x4*)(bb + (((c0 + 1) ^ sn) << 4));
        i32x8 bv = {blo.x, blo.y, blo.z, blo.w, bhi.x, bhi.y, bhi.z, bhi.w};
        // cbsz=0 (A fp8 e4m3), blgp=0 (B fp8 e4m3), scales = e8m0 127 = 1.0
        acc[j] = __builtin_amdgcn_mfma_scale_f32_32x32x64_f8f6f4(
            av, bv, acc[j], 0, 0, 0, 127, 0, 127);
      }
    }

    // ---- epilogue: gram -> S -> hinge/same select, single accumulator ----
    float s = 0.f;
#pragma unroll
    for (int j = 0; j < 2; ++j) {
#pragma unroll
      for (int g2 = 0; g2 < 16; ++g2) {
        float S = sqa_s[g2] + sqb_s[j] - acc[j][g2] * (1.0f / 128.0f);
        float h = fmaxf(0.f, 1.f - S);
        s += (laaf[g2] == labf[j]) ? S : h;
      }
    }
    stt += ((bi == bj) ? 1.0f : 2.0f) * s;  // off-diagonal tiles count twice

    tile = ntile; bi = nbi; bj = nbj; cur ^= 1;
  }

  // ---- once per block: reduce 8 waves, 1 atomic ----
#pragma unroll
  for (int off = 32; off; off >>= 1) stt += __shfl_down(stt, off);
  if (lane == 0) red[w] = stt;
  __syncthreads();
  if (t == 0) {
    float a = 0.f;
#pragma unroll
    for (int k = 0; k < 8; k++) a += red[k];
    atomicAdd(&accg[0], a);
  }
}

// ---------------------------------------------------------------------------
// Kernel 3: final scalar
// ---------------------------------------------------------------------------
__global__ void finalize_kernel(const float* __restrict__ accg,
                                float* __restrict__ out) {
  out[0] = 10.0f * accg[0] * (1.0f / ((float)NROWS * (float)NROWS));
}

extern "C" void kernel_launch(void* const* d_in, const int* in_sizes, int n_in,
                              void* d_out, int out_size, void* d_ws,
                              size_t ws_size, hipStream_t stream) {
  // inputs: 0=merged (unused), 1=input1 (unused), 2=samples, 3=labels
  const float* samples = (const float*)d_in[2];
  const int*   labels  = (const int*)d_in[3];

  char* ws = (char*)d_ws;
  unsigned char* sf8 = (unsigned char*)ws;                     // 2 MiB fp8
  float2* meta = (float2*)(ws + (size_t)NROWS * KDIM);         // 64 KiB
  float* accg  = (float*)(ws + (size_t)NROWS * KDIM + NROWS * 8);  // 8 B
  float* out   = (float*)d_out;

  prep_kernel<<<NROWS, 128, 0, stream>>>(samples, labels, sf8, meta, accg);
  pair_kernel<<<GRID, 512, 0, stream>>>(sf8, meta, accg);
  finalize_kernel<<<1, 1, 0, stream>>>(accg, out);
}

// Round 3
// 122.391 us; speedup vs baseline: 1.1144x; 1.0179x over previous
//
#include <hip/hip_runtime.h>

#define NROWS 8192
#define KDIM  256
#define NT    64                  // NROWS / 128
#define NBLK  (NT * (NT + 1) / 2) // 2080 upper-triangular 128x128 tiles
#define GRID  256                 // persistent blocks; 8-9 tiles each

typedef __attribute__((ext_vector_type(4)))  float f32x4;
typedef __attribute__((ext_vector_type(16))) float f32x16;
typedef __attribute__((ext_vector_type(4)))  int   i32x4;
typedef __attribute__((ext_vector_type(8)))  int   i32x8;

// async global->LDS, 16B per lane; LDS dest is wave-uniform base + lane*16
#define GLD(gp, lp)                                                            \
  __builtin_amdgcn_global_load_lds(                                            \
      (const __attribute__((address_space(1))) void*)(gp),                     \
      (__attribute__((address_space(3))) void*)(lp), 16, 0, 0)

// ---------------------------------------------------------------------------
// Kernel 1: fp32 -> fp8 e4m3 (OCP) convert + per-row meta {sumsq/256, label}.
// Also zeroes out[0] (pair_kernel atomics accumulate the final scalar there).
// ---------------------------------------------------------------------------
__global__ void prep_kernel(const float* __restrict__ samples,
                            const int* __restrict__ labels,
                            unsigned char* __restrict__ sf8,
                            float2* __restrict__ meta,
                            float* __restrict__ out) {
  int row = blockIdx.x, t = threadIdx.x;  // t in [0,128)
  float2 v2 = ((const float2*)samples)[(size_t)row * 128 + t];
  int pk = __builtin_amdgcn_cvt_pk_fp8_f32(v2.x, v2.y, 0, false);
  ((unsigned short*)sf8)[(size_t)row * 128 + t] = (unsigned short)(pk & 0xffff);
  float p = v2.x * v2.x + v2.y * v2.y;
#pragma unroll
  for (int off = 32; off; off >>= 1) p += __shfl_down(p, off);
  __shared__ float ws2[2];
  if ((t & 63) == 0) ws2[t >> 6] = p;
  __syncthreads();
  if (t == 0) {
    float tot = ws2[0] + ws2[1];
    meta[row] = make_float2(tot * (1.0f / 256.0f), (float)labels[row]);
  }
  if (row == 0 && t == 0) out[0] = 0.0f;
}

// decode triangular block index b -> (bi, bj), bi <= bj  (verified absmax 0.0)
__device__ inline void decode_tile(int b, int& bi, int& bj) {
  float disc = (2.0f * NT + 1.0f) * (2.0f * NT + 1.0f) - 8.0f * (float)b;
  bi = (int)(((2.0f * NT + 1.0f) - sqrtf(disc)) * 0.5f);
  if (bi < 0) bi = 0;
  if (bi > NT - 1) bi = NT - 1;
  while (bi > 0 && (bi * NT - bi * (bi - 1) / 2) > b) --bi;
  while (((bi + 1) * NT - (bi + 1) * bi / 2) <= b) ++bi;
  bj = bi + (b - (bi * NT - bi * (bi - 1) / 2));
}

// ---------------------------------------------------------------------------
// Kernel 2: persistent blocks, tile-level double-buffered fp8 Gram tiles.
// 512 threads = 8 waves, each wave a 32x64 quadrant (1x2 grid of 32x32x64
// MX-scaled MFMA; scale = e8m0 127 = 1.0, numerically plain fp8).
// DEFERRED EPILOGUE (T15): two acc banks ping-pong; tile t's epilogue VALU
// interleaves with tile t+1's MFMA phase (separate pipes, MFMA chain-stall
// issue slots absorb it). Per tile: ONE barrier; 64KB prefetch flies behind
// MFMA. Loss accumulates in one register; one reduction + 1 scaled atomic
// directly into out[0] per block (finalize kernel eliminated).
// ---------------------------------------------------------------------------
__global__ __launch_bounds__(512, 1) void pair_kernel(
    const unsigned char* __restrict__ sf8, const float2* __restrict__ meta,
    float* __restrict__ out) {

  __shared__ __align__(16) unsigned char As[2][128 * 256];
  __shared__ __align__(16) unsigned char Bs[2][128 * 256];
  __shared__ float red[8];

  int t = threadIdx.x;
  int lane = t & 63;
  int w = t >> 6;               // 0..7
  int wm = w >> 1, wn = w & 1;  // wave quadrant: rows wm*32+, cols wn*64+
  int lr = lane >> 4, pc = lane & 15;  // staging: row-in-region, phys chunk
  int l31 = lane & 31;                 // fragment row/col within 32
  int hk  = lane >> 5;                 // k-half selector (0/1)

  float stt = 0.f;

  // stage tile (bi,bj) into buffer `buf`: 32 regions x 1KB per matrix,
  // XOR-16B swizzle applied on the GLOBAL side (LDS base stays wave-uniform)
  auto stage = [&](int bi_, int bj_, int buf) {
    int rA = bi_ * 128, rB = bj_ * 128;
#pragma unroll
    for (int p = 0; p < 4; ++p) {
      int region = p * 8 + w;
      int rr = region * 4 + lr;
      int c = pc ^ (rr & 15);
      GLD(sf8 + (size_t)(rA + rr) * KDIM + c * 16, &As[buf][region * 1024]);
      GLD(sf8 + (size_t)(rB + rr) * KDIM + c * 16, &Bs[buf][region * 1024]);
    }
  };

  int tile = blockIdx.x;
  int bi, bj;
  decode_tile(tile, bi, bj);
  stage(bi, bj, 0);
  int cur = 0;

  // deferred-epilogue state: scalars for the PREVIOUS tile (reloaded each
  // iteration; meta is L2-resident) + two acc banks (static indexing only)
  int pbi = 0, pbj = 0;
  float sqa[16], laa[16], sqb[2], labv[2], pwt = 1.f;
  f32x16 accA[2], accB[2];

  // load per-row scalars for tile (pbi_,pbj_); issued BEFORE prefetch GLDs so
  // their (in-order) vmcnt waits don't force prefetch completion.
  // C/D layout (32x32): col = lane&31, row = (reg&3)+8*(reg>>2)+4*(lane>>5)
  auto load_scalars = [&](int pbi_, int pbj_) {
#pragma unroll
    for (int g = 0; g < 4; ++g) {
      int gr = pbi_ * 128 + wm * 32 + g * 8 + 4 * hk;  // rows gr..gr+3
      f32x4 m0 = *(const f32x4*)(meta + gr);
      f32x4 m1 = *(const f32x4*)(meta + gr + 2);
      sqa[g * 4 + 0] = m0.x; laa[g * 4 + 0] = m0.y;
      sqa[g * 4 + 1] = m0.z; laa[g * 4 + 1] = m0.w;
      sqa[g * 4 + 2] = m1.x; laa[g * 4 + 2] = m1.y;
      sqa[g * 4 + 3] = m1.z; laa[g * 4 + 3] = m1.w;
    }
#pragma unroll
    for (int j = 0; j < 2; ++j) {
      float2 mb = meta[pbj_ * 128 + wn * 64 + j * 32 + l31];
      sqb[j] = mb.x; labv[j] = mb.y;
    }
    pwt = (pbi_ == pbj_) ? 1.0f : 2.0f;
  };

  // MFMA phase on buf[cur] into the given acc bank: 8x mfma 32x32x64 fp8 (MX)
  auto domfma = [&](f32x16 (&acc)[2]) {
#pragma unroll
    for (int j = 0; j < 2; ++j)
#pragma unroll
      for (int e = 0; e < 16; ++e) acc[j][e] = 0.f;
#pragma unroll
    for (int kt = 0; kt < 4; ++kt) {
      int c0 = kt * 4 + hk * 2;  // logical 16B-chunk pair for this lane
      int m = wm * 32 + l31;
      const unsigned char* ab = &As[cur][m * 256];
      int sm = m & 15;
      i32x4 alo = *(const i32x4*)(ab + ((c0 ^ sm) << 4));
      i32x4 ahi = *(const i32x4*)(ab + (((c0 + 1) ^ sm) << 4));
      i32x8 av = {alo.x, alo.y, alo.z, alo.w, ahi.x, ahi.y, ahi.z, ahi.w};
#pragma unroll
      for (int j = 0; j < 2; ++j) {
        int n = wn * 64 + j * 32 + l31;
        const unsigned char* bb = &Bs[cur][n * 256];
        int sn = n & 15;
        i32x4 blo = *(const i32x4*)(bb + ((c0 ^ sn) << 4));
        i32x4 bhi = *(const i32x4*)(bb + (((c0 + 1) ^ sn) << 4));
        i32x8 bv = {blo.x, blo.y, blo.z, blo.w, bhi.x, bhi.y, bhi.z, bhi.w};
        // cbsz=0 (A fp8 e4m3), blgp=0 (B fp8 e4m3), scales = e8m0 127 = 1.0
        acc[j] = __builtin_amdgcn_mfma_scale_f32_32x32x64_f8f6f4(
            av, bv, acc[j], 0, 0, 0, 127, 0, 127);
      }
    }
  };

  // epilogue for the deferred tile: gram -> S -> hinge/same, one accumulator
  auto epi = [&](const f32x16 (&acc)[2]) {
    float s = 0.f;
#pragma unroll
    for (int j = 0; j < 2; ++j) {
#pragma unroll
      for (int g2 = 0; g2 < 16; ++g2) {
        float S = sqa[g2] + sqb[j] - acc[j][g2] * (1.0f / 128.0f);
        float h = fmaxf(0.f, 1.f - S);
        s += (laa[g2] == labv[j]) ? S : h;
      }
    }
    stt += pwt * s;
  };

  int k = 0;
  while (tile < NBLK) {
    int ntile = tile + GRID;
    int nbi = 0, nbj = 0;
    bool have_next = ntile < NBLK;
    if (have_next) decode_tile(ntile, nbi, nbj);

    __syncthreads();  // buf[cur] staging complete (vmcnt drain at barrier)

    bool have_prev = (k > 0);
    if (have_prev) load_scalars(pbi, pbj);  // L2-hit loads, consumed in epi

    if (have_next) stage(nbi, nbj, cur ^ 1);  // async prefetch, other buffer

    // MFMA(cur tile) interleaved (separate pipes) with epilogue(prev tile)
    if (k & 1) {
      domfma(accB);
      if (have_prev) epi(accA);
    } else {
      domfma(accA);
      if (have_prev) epi(accB);
    }

    pbi = bi; pbj = bj;
    tile = ntile; bi = nbi; bj = nbj; cur ^= 1; ++k;
  }

  // drain: epilogue for the last computed tile (bank = parity of k-1)
  load_scalars(pbi, pbj);
  if ((k - 1) & 1) epi(accB);
  else             epi(accA);

  // ---- once per block: reduce 8 waves, 1 scaled atomic into out[0] ----
#pragma unroll
  for (int off = 32; off; off >>= 1) stt += __shfl_down(stt, off);
  if (lane == 0) red[w] = stt;
  __syncthreads();
  if (t == 0) {
    float a = 0.f;
#pragma unroll
    for (int q = 0; q < 8; q++) a += red[q];
    atomicAdd(&out[0], a * (10.0f / ((float)NROWS * (float)NROWS)));
  }
}

extern "C" void kernel_launch(void* const* d_in, const int* in_sizes, int n_in,
                              void* d_out, int out_size, void* d_ws,
                              size_t ws_size, hipStream_t stream) {
  // inputs: 0=merged (unused), 1=input1 (unused), 2=samples, 3=labels
  const float* samples = (const float*)d_in[2];
  const int*   labels  = (const int*)d_in[3];

  char* ws = (char*)d_ws;
  unsigned char* sf8 = (unsigned char*)ws;                  // 2 MiB fp8
  float2* meta = (float2*)(ws + (size_t)NROWS * KDIM);      // 64 KiB
  float* out   = (float*)d_out;

  prep_kernel<<<NROWS, 128, 0, stream>>>(samples, labels, sf8, meta, out);
  pair_kernel<<<GRID, 512, 0, stream>>>(sf8, meta, out);
}